// Round 1
// baseline (1170.626 us; speedup 1.0000x reference)
//
#include <hip/hip_runtime.h>
#include <hip/hip_bf16.h>

// Problem constants (b=8, c=512, h=64, w=64, n=4096, heads=16, hd=32)
#define BATCH 8
#define CDIM 512
#define NTOK 4096
#define NHEAD 16
#define HD 32
#define EPS 1e-5f

// ---------------- GEMM: Y[b,d,n] = act( sum_c W[d,c] * X[b,c,n] ) + bias ----------------
// M=512 (d), K=512 (c), N=4096 (n). Row-major everywhere. 128x128 tile, BK=8, 8x8/thread.
#define BM 128
#define BN 128
#define BK 8
#define TM 8
#define TN 8

template<int ACT>  // 0: none, 1: elu(x)+1
__global__ __launch_bounds__(256)
void gemm_wx(const float* __restrict__ W, const float* __restrict__ Xall,
             float* __restrict__ Yall, const float* __restrict__ bias) {
    const int b  = blockIdx.z;
    const int m0 = blockIdx.y * BM;   // d tile
    const int n0 = blockIdx.x * BN;   // n tile
    const float* X = Xall + (size_t)b * CDIM * NTOK;
    float*       Y = Yall + (size_t)b * CDIM * NTOK;

    __shared__ __align__(16) float As[BK][BM];   // As[k][m] = W[m0+m][k0+k]
    __shared__ __align__(16) float Bs[BK][BN];   // Bs[k][n] = X[k0+k][n0+n]

    const int tid   = threadIdx.x;
    const int a_row = tid >> 1;          // 0..127
    const int a_col = (tid & 1) * 4;     // 0 or 4
    const int b_row = tid >> 5;          // 0..7
    const int b_col = (tid & 31) * 4;    // 0..124
    const int ty = tid >> 4;             // 0..15
    const int tx = tid & 15;             // 0..15

    float acc[TM][TN] = {};

    for (int k0 = 0; k0 < CDIM; k0 += BK) {
        float4 av = *reinterpret_cast<const float4*>(&W[(size_t)(m0 + a_row) * CDIM + k0 + a_col]);
        As[a_col + 0][a_row] = av.x;
        As[a_col + 1][a_row] = av.y;
        As[a_col + 2][a_row] = av.z;
        As[a_col + 3][a_row] = av.w;
        float4 bv = *reinterpret_cast<const float4*>(&X[(size_t)(k0 + b_row) * NTOK + n0 + b_col]);
        *reinterpret_cast<float4*>(&Bs[b_row][b_col]) = bv;
        __syncthreads();
        #pragma unroll
        for (int k = 0; k < BK; ++k) {
            float4 ra0 = *reinterpret_cast<const float4*>(&As[k][ty * TM]);
            float4 ra1 = *reinterpret_cast<const float4*>(&As[k][ty * TM + 4]);
            float4 rb0 = *reinterpret_cast<const float4*>(&Bs[k][tx * TN]);
            float4 rb1 = *reinterpret_cast<const float4*>(&Bs[k][tx * TN + 4]);
            float ra[TM] = {ra0.x, ra0.y, ra0.z, ra0.w, ra1.x, ra1.y, ra1.z, ra1.w};
            float rb[TN] = {rb0.x, rb0.y, rb0.z, rb0.w, rb1.x, rb1.y, rb1.z, rb1.w};
            #pragma unroll
            for (int i = 0; i < TM; ++i)
                #pragma unroll
                for (int j = 0; j < TN; ++j)
                    acc[i][j] += ra[i] * rb[j];
        }
        __syncthreads();
    }

    #pragma unroll
    for (int i = 0; i < TM; ++i) {
        const int d = m0 + ty * TM + i;
        const float bval = bias ? bias[d] : 0.0f;
        float row[TN];
        #pragma unroll
        for (int j = 0; j < TN; ++j) {
            float v = acc[i][j] + bval;
            if (ACT == 1) v = (v > 0.0f) ? (v + 1.0f) : __expf(v);
            row[j] = v;
        }
        float* dst = &Y[(size_t)d * NTOK + n0 + tx * TN];
        *reinterpret_cast<float4*>(dst)     = make_float4(row[0], row[1], row[2], row[3]);
        *reinterpret_cast<float4*>(dst + 4) = make_float4(row[4], row[5], row[6], row[7]);
    }
}

// ---------------- Ksum[b*512+c] = sum_n Kf[b,c,n] ----------------
__global__ __launch_bounds__(256)
void ksum_kernel(const float* __restrict__ Kf, float* __restrict__ Ksum) {
    const int row = blockIdx.x;  // b*512 + c, 4096 rows
    const float* p = Kf + (size_t)row * NTOK;
    float acc = 0.0f;
    for (int i = threadIdx.x; i < NTOK; i += 256) acc += p[i];
    __shared__ float red[256];
    red[threadIdx.x] = acc;
    __syncthreads();
    for (int s = 128; s > 0; s >>= 1) {
        if (threadIdx.x < s) red[threadIdx.x] += red[threadIdx.x + s];
        __syncthreads();
    }
    if (threadIdx.x == 0) Ksum[row] = red[0];
}

// ---------------- Middle: per token KV/Z/out; writes out_tok in-place over V ----------------
// Block = 256 threads = 4 waves; wave w handles token n = base+w of batch b.
__global__ __launch_bounds__(256)
void middle_kernel(const float* __restrict__ Qf, const float* __restrict__ Kf,
                   float* Vio, const float* __restrict__ Ksum) {
    const int blk = blockIdx.x;            // 8192 blocks
    const int b = blk >> 10;               // 1024 blocks per batch
    const int n = ((blk & 1023) << 2) + (threadIdx.x >> 6);
    const int w = threadIdx.x >> 6;
    const int lane = threadIdx.x & 63;

    __shared__ float sQ[4][CDIM];
    __shared__ float sK[4][CDIM];
    __shared__ float sV[4][CDIM];
    __shared__ float sKV[4][HD][HD + 1];   // [d][m], padded
    __shared__ float sKs[CDIM];
    __shared__ float sZ[4][NHEAD];

    for (int c = threadIdx.x; c < CDIM; c += 256) sKs[c] = Ksum[b * CDIM + c];

    const size_t base = ((size_t)b * CDIM) * NTOK + n;
    #pragma unroll
    for (int i = 0; i < 8; ++i) {
        const int c = i * 64 + lane;
        const size_t off = base + (size_t)c * NTOK;
        sQ[w][c] = Qf[off];
        sK[w][c] = Kf[off];
        sV[w][c] = Vio[off];
    }
    __syncthreads();

    // KV[d][m] = sum_h K[h*32+d] * V[h*32+m]; lane: d = lane&31, m-half = lane>>5
    const int d  = lane & 31;
    const int mh = lane >> 5;
    float kreg[NHEAD];
    #pragma unroll
    for (int h = 0; h < NHEAD; ++h) kreg[h] = sK[w][h * HD + d];
    #pragma unroll
    for (int mm = 0; mm < 16; ++mm) {
        const int m = mh * 16 + mm;
        float acc = 0.0f;
        #pragma unroll
        for (int h = 0; h < NHEAD; ++h) acc += kreg[h] * sV[w][h * HD + m];
        sKV[w][d][m] = acc;
    }
    // Z[h] = 1/(sum_d Q[h*32+d]*Ksum[h*32+d] + EPS)
    if (lane < NHEAD) {
        const int h = lane;
        float acc = 0.0f;
        #pragma unroll
        for (int dd = 0; dd < HD; ++dd) acc += sQ[w][h * HD + dd] * sKs[h * HD + dd];
        sZ[w][h] = 1.0f / (acc + EPS);
    }
    __syncthreads();

    // out[c=h*32+m] = Z[h] * sum_d Q[h*32+d] * KV[d][m]; write over V
    #pragma unroll
    for (int i = 0; i < 8; ++i) {
        const int c = i * 64 + lane;
        const int h = c >> 5, m = c & 31;
        float acc = 0.0f;
        #pragma unroll
        for (int dd = 0; dd < HD; ++dd) acc += sQ[w][h * HD + dd] * sKV[w][dd][m];
        Vio[base + (size_t)c * NTOK] = acc * sZ[w][h];
    }
}

// ---------------- launch ----------------
extern "C" void kernel_launch(void* const* d_in, const int* in_sizes, int n_in,
                              void* d_out, int out_size, void* d_ws, size_t ws_size,
                              hipStream_t stream) {
    const float* q  = (const float*)d_in[0];
    const float* k  = (const float*)d_in[1];
    const float* v  = (const float*)d_in[2];
    const float* Wq = (const float*)d_in[3];
    const float* Wk = (const float*)d_in[4];
    const float* Wv = (const float*)d_in[5];
    const float* Wp = (const float*)d_in[6];
    const float* bp = (const float*)d_in[7];
    float* out = (float*)d_out;

    const size_t slab = (size_t)BATCH * CDIM * NTOK;  // 16,777,216 floats
    float* Qf = (float*)d_ws;
    float* Kf = Qf + slab;
    float* Vc = Kf + slab;
    float* Ks = Vc + slab;   // 4096 floats

    dim3 bb(256);
    dim3 gg(NTOK / BN, CDIM / BM, BATCH);  // 32 x 4 x 8

    gemm_wx<1><<<gg, bb, 0, stream>>>(Wq, q, Qf, nullptr);
    gemm_wx<1><<<gg, bb, 0, stream>>>(Wk, k, Kf, nullptr);
    gemm_wx<0><<<gg, bb, 0, stream>>>(Wv, v, Vc, nullptr);
    ksum_kernel<<<dim3(BATCH * CDIM), bb, 0, stream>>>(Kf, Ks);
    middle_kernel<<<dim3(BATCH * NTOK / 4), bb, 0, stream>>>(Qf, Kf, Vc, Ks);
    gemm_wx<0><<<gg, bb, 0, stream>>>(Wp, Vc, out, bp);
}

// Round 2
// 273.790 us; speedup vs baseline: 4.2756x; 4.2756x over previous
//
#include <hip/hip_runtime.h>
#include <hip/hip_bf16.h>

#define BATCH 8
#define CD 512
#define NT 4096
#define EPSV 1e-5f

using u16x8 = __attribute__((ext_vector_type(8))) unsigned short;
using bf8   = __attribute__((ext_vector_type(8))) short;
using f32x4 = __attribute__((ext_vector_type(4))) float;

__device__ __forceinline__ float b2f(unsigned short u) {
    union { unsigned int i; float f; } x; x.i = ((unsigned int)u) << 16; return x.f;
}
__device__ __forceinline__ unsigned short f2b(float f) {
    unsigned int x = __float_as_uint(f);
    unsigned int r = (x + 0x7fffu + ((x >> 16) & 1u)) >> 16;
    return (unsigned short)r;
}
__device__ __forceinline__ void gload_lds16(const void* g, void* l) {
    __builtin_amdgcn_global_load_lds((const __attribute__((address_space(1))) unsigned int*)g,
                                     (__attribute__((address_space(3))) unsigned int*)l, 16, 0, 0);
}

// ---------- W fp32 -> bf16 (row-major kept) ----------
__global__ __launch_bounds__(256)
void wconv(const float* __restrict__ W0, const float* __restrict__ W1,
           const float* __restrict__ W2, const float* __restrict__ W3,
           unsigned short* __restrict__ Wb) {
    const float* src = (blockIdx.y == 0) ? W0 : (blockIdx.y == 1) ? W1 : (blockIdx.y == 2) ? W2 : W3;
    unsigned short* dst = Wb + (size_t)blockIdx.y * CD * CD;
    const int base = blockIdx.x * 4096 + threadIdx.x * 16;
    u16x8 o0, o1;
    #pragma unroll
    for (int i = 0; i < 4; ++i) {
        float4 v = *reinterpret_cast<const float4*>(src + base + i * 4);
        unsigned short* t = (i < 2) ? (unsigned short*)&o0 : (unsigned short*)&o1;
        t[(i & 1) * 4 + 0] = f2b(v.x); t[(i & 1) * 4 + 1] = f2b(v.y);
        t[(i & 1) * 4 + 2] = f2b(v.z); t[(i & 1) * 4 + 3] = f2b(v.w);
    }
    *(u16x8*)(dst + base)     = o0;
    *(u16x8*)(dst + base + 8) = o1;
}

// ---------- transpose + convert: [b][c][n] f32 -> [b][n][c] bf16, for q,k,v ----------
__global__ __launch_bounds__(256)
void tconv3(const float* __restrict__ X0, const float* __restrict__ X1, const float* __restrict__ X2,
            unsigned short* __restrict__ Y0, unsigned short* __restrict__ Y1, unsigned short* __restrict__ Y2) {
    __shared__ float sT[64][65];
    const int mat = blockIdx.z >> 3;
    const int b   = blockIdx.z & 7;
    const float* X = (mat == 0) ? X0 : (mat == 1) ? X1 : X2;
    unsigned short* Y = (mat == 0) ? Y0 : (mat == 1) ? Y1 : Y2;
    const int n0 = blockIdx.x * 64, c0 = blockIdx.y * 64;
    const float* Xb = X + (size_t)b * CD * NT;
    unsigned short* Yb = Y + (size_t)b * NT * CD;
    const int tid = threadIdx.x;
    const int rh = tid >> 4, f4 = tid & 15;
    #pragma unroll
    for (int p = 0; p < 4; ++p) {
        const int c = p * 16 + rh;
        float4 v = *reinterpret_cast<const float4*>(Xb + (size_t)(c0 + c) * NT + n0 + f4 * 4);
        sT[f4 * 4 + 0][c] = v.x; sT[f4 * 4 + 1][c] = v.y;
        sT[f4 * 4 + 2][c] = v.z; sT[f4 * 4 + 3][c] = v.w;
    }
    __syncthreads();
    const int nl = tid >> 2, cp = tid & 3;
    u16x8 o0, o1;
    #pragma unroll
    for (int e = 0; e < 8; ++e) o0[e] = f2b(sT[nl][cp * 16 + e]);
    #pragma unroll
    for (int e = 0; e < 8; ++e) o1[e] = f2b(sT[nl][cp * 16 + 8 + e]);
    unsigned short* dst = Yb + (size_t)(n0 + nl) * CD + c0 + cp * 16;
    *(u16x8*)dst       = o0;
    *(u16x8*)(dst + 8) = o1;
}

// ---------- NT-GEMM: D[i][j] = sum_k A[i][k]*B[j][k]; A,B row-major bf16 with K=512 ----------
// ACT: 1 = elu(x)+1.  OUTF32: 0 -> bf16 out, 1 -> f32 out + bias[i]
template<int ACT, int OUTF32>
__global__ __launch_bounds__(256)
void gemm_rr(const unsigned short* __restrict__ A, long aBatch,
             const unsigned short* __restrict__ B, long bBatch,
             void* __restrict__ Out, const float* __restrict__ bias, int N) {
    __shared__ __align__(16) unsigned short Asm[128 * 64];
    __shared__ __align__(16) unsigned short Bsm[128 * 64];
    const int b  = blockIdx.z;
    const int i0 = blockIdx.y * 128;
    const int j0 = blockIdx.x * 128;
    const unsigned short* Ab = A + (size_t)b * aBatch;
    const unsigned short* Bb = B + (size_t)b * bBatch;
    const int tid  = threadIdx.x;
    const int lane = tid & 63;
    const int wv   = tid >> 6;
    const int wi = wv >> 1, wj = wv & 1;

    f32x4 acc[4][4];
    #pragma unroll
    for (int m = 0; m < 4; ++m)
        #pragma unroll
        for (int j = 0; j < 4; ++j)
            acc[m][j] = (f32x4){0.f, 0.f, 0.f, 0.f};

    for (int k0 = 0; k0 < CD; k0 += 64) {
        #pragma unroll
        for (int it = 0; it < 4; ++it) {
            const int idx = it * 256 + tid;
            const int r = idx >> 3, p = idx & 7;
            const int ps = p ^ (r & 7);
            gload_lds16(Ab + (size_t)(i0 + r) * CD + k0 + ps * 8, (char*)Asm + idx * 16);
            gload_lds16(Bb + (size_t)(j0 + r) * CD + k0 + ps * 8, (char*)Bsm + idx * 16);
        }
        __syncthreads();
        #pragma unroll
        for (int kk = 0; kk < 2; ++kk) {
            bf8 af[4], bfr[4];
            #pragma unroll
            for (int m = 0; m < 4; ++m) {
                const int r  = wi * 64 + m * 16 + (lane & 15);
                const int kp = kk * 4 + (lane >> 4);
                af[m] = *(const bf8*)((const char*)Asm + r * 128 + ((kp ^ (r & 7)) * 16));
            }
            #pragma unroll
            for (int j = 0; j < 4; ++j) {
                const int r  = wj * 64 + j * 16 + (lane & 15);
                const int kp = kk * 4 + (lane >> 4);
                bfr[j] = *(const bf8*)((const char*)Bsm + r * 128 + ((kp ^ (r & 7)) * 16));
            }
            #pragma unroll
            for (int m = 0; m < 4; ++m)
                #pragma unroll
                for (int j = 0; j < 4; ++j)
                    acc[m][j] = __builtin_amdgcn_mfma_f32_16x16x32_bf16(af[m], bfr[j], acc[m][j], 0, 0, 0);
        }
        __syncthreads();
    }

    const size_t oBatch = (size_t)NT * CD;
    #pragma unroll
    for (int m = 0; m < 4; ++m) {
        const int ib = i0 + wi * 64 + m * 16 + (lane >> 4) * 4;
        #pragma unroll
        for (int j = 0; j < 4; ++j) {
            const int jb = j0 + wj * 64 + j * 16 + (lane & 15);
            f32x4 v = acc[m][j];
            #pragma unroll
            for (int r = 0; r < 4; ++r) {
                float val = v[r];
                if (ACT) val = (val > 0.f) ? (val + 1.f) : __expf(val);
                if (OUTF32) {
                    ((float*)Out)[(size_t)b * oBatch + (size_t)(ib + r) * N + jb] = val + bias[ib + r];
                } else {
                    ((unsigned short*)Out)[(size_t)b * oBatch + (size_t)(ib + r) * N + jb] = f2b(val);
                }
            }
        }
    }
}

// ---------- Ksum[b][c] = sum_n K[b][n][c]  (2-pass, deterministic) ----------
__global__ __launch_bounds__(256)
void ksum_part(const unsigned short* __restrict__ K, float* __restrict__ part) {
    const int b = blockIdx.y, ch = blockIdx.x, t = threadIdx.x;
    const unsigned short* base = K + ((size_t)b * NT + ch * 256) * CD;
    float a0 = 0.f, a1 = 0.f;
    for (int nn = 0; nn < 256; ++nn) {
        a0 += b2f(base[(size_t)nn * CD + t]);
        a1 += b2f(base[(size_t)nn * CD + 256 + t]);
    }
    float* p = part + (size_t)(b * 16 + ch) * CD;
    p[t] = a0; p[256 + t] = a1;
}
__global__ __launch_bounds__(512)
void ksum_red(const float* __restrict__ part, float* __restrict__ Ks) {
    const int b = blockIdx.x, c = threadIdx.x;
    float s = 0.f;
    #pragma unroll
    for (int i = 0; i < 16; ++i) s += part[(size_t)(b * 16 + i) * CD + c];
    Ks[b * CD + c] = s;
}

// ---------- middle: S = Q K^T (per token), Z, out = Z * S V ; token-major bf16 ----------
__global__ __launch_bounds__(256)
void middle(const unsigned short* __restrict__ Q, const unsigned short* __restrict__ K,
            const unsigned short* __restrict__ V, const float* __restrict__ Ksum,
            unsigned short* __restrict__ T) {
    __shared__ __align__(16) unsigned short sK[16][520];  // 520*2B stride -> toks on distinct banks
    __shared__ __align__(16) unsigned short sV[16][520];
    const int b  = blockIdx.y;
    const int n0 = blockIdx.x * 16;
    const int tid = threadIdx.x;
    const int lane = tid & 63, wv = tid >> 6;
    const size_t rowbase = (size_t)b * NT + n0;

    #pragma unroll
    for (int i = 0; i < 4; ++i) {
        const int row = wv * 4 + i;
        gload_lds16(K + (rowbase + row) * CD + lane * 8, (char*)&sK[row][0] + lane * 16);
        gload_lds16(V + (rowbase + row) * CD + lane * 8, (char*)&sV[row][0] + lane * 16);
    }
    __syncthreads();

    const int tok = tid >> 4, h = tid & 15;
    const unsigned short* qp = Q + (rowbase + tok) * CD + h * 32;
    float q[32];
    #pragma unroll
    for (int i = 0; i < 4; ++i) {
        u16x8 u = *(const u16x8*)(qp + i * 8);
        #pragma unroll
        for (int e = 0; e < 8; ++e) q[i * 8 + e] = b2f(u[e]);
    }

    float S[16];
    #pragma unroll
    for (int hp = 0; hp < 16; ++hp) {
        float s = 0.f;
        #pragma unroll
        for (int i = 0; i < 4; ++i) {
            u16x8 u = *(const u16x8*)(&sK[tok][hp * 32 + i * 8]);
            #pragma unroll
            for (int e = 0; e < 8; ++e) s += q[i * 8 + e] * b2f(u[e]);
        }
        S[hp] = s;
    }

    const float* ks = Ksum + b * CD + h * 32;
    float zden = EPSV;
    #pragma unroll
    for (int i = 0; i < 8; ++i) {
        float4 kv = *reinterpret_cast<const float4*>(ks + i * 4);
        zden += q[i * 4 + 0] * kv.x + q[i * 4 + 1] * kv.y + q[i * 4 + 2] * kv.z + q[i * 4 + 3] * kv.w;
    }
    const float z = 1.f / zden;

    float o[32] = {};
    #pragma unroll
    for (int hp = 0; hp < 16; ++hp) {
        const float s = S[hp];
        #pragma unroll
        for (int i = 0; i < 4; ++i) {
            u16x8 u = *(const u16x8*)(&sV[tok][hp * 32 + i * 8]);
            #pragma unroll
            for (int e = 0; e < 8; ++e) o[i * 8 + e] += s * b2f(u[e]);
        }
    }

    unsigned short* tp = T + (rowbase + tok) * CD + h * 32;
    #pragma unroll
    for (int i = 0; i < 4; ++i) {
        u16x8 u;
        #pragma unroll
        for (int e = 0; e < 8; ++e) u[e] = f2b(o[i * 8 + e] * z);
        *(u16x8*)(tp + i * 8) = u;
    }
}

// ---------- launch ----------
extern "C" void kernel_launch(void* const* d_in, const int* in_sizes, int n_in,
                              void* d_out, int out_size, void* d_ws, size_t ws_size,
                              hipStream_t stream) {
    const float* q  = (const float*)d_in[0];
    const float* k  = (const float*)d_in[1];
    const float* v  = (const float*)d_in[2];
    const float* Wq = (const float*)d_in[3];
    const float* Wk = (const float*)d_in[4];
    const float* Wv = (const float*)d_in[5];
    const float* Wp = (const float*)d_in[6];
    const float* bp = (const float*)d_in[7];
    float* out = (float*)d_out;

    const size_t slab = (size_t)BATCH * NT * CD;      // elems per full tensor
    const long   perB = (long)NT * CD;                // per-batch stride (elems)
    unsigned short* B0 = (unsigned short*)d_ws;       // qT, later V-projected
    unsigned short* B1 = B0 + slab;                   // kT, later middle-out T
    unsigned short* B2 = B1 + slab;                   // vT
    unsigned short* B3 = B2 + slab;                   // Q projected
    unsigned short* B4 = B3 + slab;                   // K projected
    unsigned short* Wb = B4 + slab;                   // 4 x 512x512 bf16
    float* Kpart = (float*)(Wb + 4 * CD * CD);        // 8*16*512 f32
    float* Ks    = Kpart + 8 * 16 * CD;               // 8*512 f32

    wconv <<<dim3(64, 4),    256, 0, stream>>>(Wq, Wk, Wv, Wp, Wb);
    tconv3<<<dim3(64, 8, 24), 256, 0, stream>>>(q, k, v, B0, B1, B2);

    const unsigned short* Wqb = Wb;
    const unsigned short* Wkb = Wb + (size_t)CD * CD;
    const unsigned short* Wvb = Wb + (size_t)2 * CD * CD;
    const unsigned short* Wpb = Wb + (size_t)3 * CD * CD;

    dim3 gq(4, 32, 8);   // j-tiles(d)=4, i-tiles(n)=32, batch
    gemm_rr<1, 0><<<gq, 256, 0, stream>>>(B0, perB, Wqb, 0, B3, nullptr, CD);
    gemm_rr<1, 0><<<gq, 256, 0, stream>>>(B1, perB, Wkb, 0, B4, nullptr, CD);
    gemm_rr<0, 0><<<gq, 256, 0, stream>>>(B2, perB, Wvb, 0, B0, nullptr, CD);

    ksum_part<<<dim3(16, 8), 256, 0, stream>>>(B4, Kpart);
    ksum_red <<<dim3(8),     512, 0, stream>>>(Kpart, Ks);

    middle<<<dim3(256, 8), 256, 0, stream>>>(B3, B4, B0, Ks, B1);

    gemm_rr<0, 1><<<dim3(32, 4, 8), 256, 0, stream>>>(Wpb, 0, B1, perB, out, bp, NT);
}